// Round 7
// baseline (109.487 us; speedup 1.0000x reference)
//
#include <hip/hip_runtime.h>

#define B_   4
#define CIN  23
#define H_   256
#define W_   512
#define CO   64

typedef float f32x4 __attribute__((ext_vector_type(4)));

// ---------------------------------------------------------------------------
// Kernel 1: 1x1 conv (23->64) + bias + relu, mean over H -> avg[B][W][CO].
// 2048 blocks x 512 thr. Tile = (b, wq): 16 w x 256 h x 23 cin = 0.375 MB;
// 16 channel-group blocks per tile (c0 = cg*4, block-uniform -> s_load weights,
// zero LDS / zero vector loads for weights in the inner loop).
//
// XCD swizzle: bid = r + 8*(cg + 16*j), tile = 16r + j -> XCD r owns the
// contiguous w-band [64r, 64r+64). Co-resident working set per XCD at
// 4 blocks/CU = 8 tiles x 0.375 MB = 3 MB < 4 MB L2 -> the 16x cg re-read is
// L2-served; adjacent-wq tiles co-reside so HBM lines are fetched once.
//
// Lane = (wl 0..15, hl 0..3); each lane computes a 4h x 4c register tile per
// i-step (FMA:load = 4:1). Wave wv covers h in [32wv, 32wv+32). Full H per
// block -> direct store, no atomics, no second kernel.
// ---------------------------------------------------------------------------
__global__ __launch_bounds__(512) void conv_mean_kernel(
    const float* __restrict__ msa,   // [B][CIN][H][W]
    const float* __restrict__ Wc,    // [CO][CIN]
    const float* __restrict__ bias,  // [CO]
    float* __restrict__ avg)         // [B][W][CO]
{
    const int bid  = blockIdx.x;
    const int r    = bid & 7;
    const int q    = bid >> 3;            // 0..255
    const int cg   = q & 15;              // channel group (block-uniform)
    const int j    = q >> 4;              // 0..15
    const int tile = 16 * r + j;          // 0..127
    const int wq   = tile >> 2;           // 0..31
    const int b    = tile & 3;
    const int c0   = cg * 4;

    const int tid  = threadIdx.x;
    const int lane = tid & 63;
    const int wv   = tid >> 6;            // 0..7 : h-chunk of 32
    const int wl   = lane & 15;           // w within tile
    const int hl   = lane >> 4;           // 0..3 : h sub-lane
    const int w    = wq * 16 + wl;

    // uniform bias -> SGPRs
    const float bs0 = bias[c0 + 0], bs1 = bias[c0 + 1];
    const float bs2 = bias[c0 + 2], bs3 = bias[c0 + 3];

    float sum0 = 0.f, sum1 = 0.f, sum2 = 0.f, sum3 = 0.f;

    for (int hb = 0; hb < 2; ++hb) {
        const int hbase = wv * 32 + hb * 16 + hl;   // lane's h set: hbase + {0,4,8,12}
        const float* xb = msa + (((size_t)b * CIN) * H_ + hbase) * W_ + w;

        // t[k][c] : 4 h-samples x 4 channels
        float t0[4], t1[4], t2[4], t3[4];
        t0[0] = bs0; t0[1] = bs1; t0[2] = bs2; t0[3] = bs3;
        t1[0] = bs0; t1[1] = bs1; t1[2] = bs2; t1[3] = bs3;
        t2[0] = bs0; t2[1] = bs1; t2[2] = bs2; t2[3] = bs3;
        t3[0] = bs0; t3[1] = bs1; t3[2] = bs2; t3[3] = bs3;

#pragma unroll
        for (int i = 0; i < CIN; ++i) {
            const float* xp = xb + (size_t)i * (H_ * W_);
            const float x0 = xp[0];
            const float x1 = xp[4 * W_];
            const float x2 = xp[8 * W_];
            const float x3 = xp[12 * W_];
            // block-uniform weight reads -> scalar pipe
            const float wk0 = Wc[(c0 + 0) * CIN + i];
            const float wk1 = Wc[(c0 + 1) * CIN + i];
            const float wk2 = Wc[(c0 + 2) * CIN + i];
            const float wk3 = Wc[(c0 + 3) * CIN + i];
            t0[0] = fmaf(wk0, x0, t0[0]); t0[1] = fmaf(wk1, x0, t0[1]);
            t0[2] = fmaf(wk2, x0, t0[2]); t0[3] = fmaf(wk3, x0, t0[3]);
            t1[0] = fmaf(wk0, x1, t1[0]); t1[1] = fmaf(wk1, x1, t1[1]);
            t1[2] = fmaf(wk2, x1, t1[2]); t1[3] = fmaf(wk3, x1, t1[3]);
            t2[0] = fmaf(wk0, x2, t2[0]); t2[1] = fmaf(wk1, x2, t2[1]);
            t2[2] = fmaf(wk2, x2, t2[2]); t2[3] = fmaf(wk3, x2, t2[3]);
            t3[0] = fmaf(wk0, x3, t3[0]); t3[1] = fmaf(wk1, x3, t3[1]);
            t3[2] = fmaf(wk2, x3, t3[2]); t3[3] = fmaf(wk3, x3, t3[3]);
        }
        sum0 += fmaxf(t0[0], 0.f) + fmaxf(t1[0], 0.f) + fmaxf(t2[0], 0.f) + fmaxf(t3[0], 0.f);
        sum1 += fmaxf(t0[1], 0.f) + fmaxf(t1[1], 0.f) + fmaxf(t2[1], 0.f) + fmaxf(t3[1], 0.f);
        sum2 += fmaxf(t0[2], 0.f) + fmaxf(t1[2], 0.f) + fmaxf(t2[2], 0.f) + fmaxf(t3[2], 0.f);
        sum3 += fmaxf(t0[3], 0.f) + fmaxf(t1[3], 0.f) + fmaxf(t2[3], 0.f) + fmaxf(t3[3], 0.f);
    }

    // 32 partials (8 wv x 4 hl) per (w, c); cross-wave reduce, no atomics
    __shared__ float red[8][4][16][4];    // 8 KiB
    f32x4 v; v.x = sum0; v.y = sum1; v.z = sum2; v.w = sum3;
    *(f32x4*)&red[wv][hl][wl][0] = v;
    __syncthreads();

    if (tid < 64) {
        const int l = tid >> 2;           // w within tile
        const int c = tid & 3;            // channel
        float s = 0.f;
#pragma unroll
        for (int k = 0; k < 8; ++k)
#pragma unroll
            for (int m = 0; m < 4; ++m) s += red[k][m][l][c];
        avg[((size_t)(b * W_ + wq * 16 + l)) * CO + c0 + c] = s * (1.0f / H_);
    }
}

// ---------------------------------------------------------------------------
// Kernel 2: out[b][wi][wj][c] = avg[b][wi][c] + avg[b][wj][c]
// Grid (wi=512, b=4) x 256 thr; each wave stores 1 KiB contiguous per iter.
// avg (512 KB) is L2-resident; output stream uses nontemporal stores.
// ---------------------------------------------------------------------------
__global__ __launch_bounds__(256) void pairs_kernel(
    const float* __restrict__ avg,  // [B][W][CO]
    float* __restrict__ out)        // [B][W][W][CO]
{
    const int b   = blockIdx.y;
    const int wi  = blockIdx.x;
    const int tid = threadIdx.x;
    const int cq  = tid & 15;   // c-quad (64 c = 16 float4)
    const int wj0 = tid >> 4;   // 0..15

    const f32x4* a4 = (const f32x4*)avg;
    const f32x4 aI = a4[(b * W_ + wi) * 16 + cq];
    f32x4* o4 = (f32x4*)out + ((size_t)(b * W_ + wi)) * W_ * 16;

#pragma unroll 4
    for (int wj = wj0; wj < W_; wj += 16) {
        const f32x4 aJ = a4[(b * W_ + wj) * 16 + cq];
        const f32x4 r = aI + aJ;
        __builtin_nontemporal_store(r, o4 + (size_t)wj * 16 + cq);
    }
}

extern "C" void kernel_launch(void* const* d_in, const int* in_sizes, int n_in,
                              void* d_out, int out_size, void* d_ws, size_t ws_size,
                              hipStream_t stream) {
    const float* msa = (const float*)d_in[0];   // (4, 23, 256, 512)
    const float* Wc  = (const float*)d_in[1];   // (64, 23)
    const float* bc  = (const float*)d_in[2];   // (64,)
    float* out = (float*)d_out;                 // (4, 512, 512, 64)
    float* avg = (float*)d_ws;                  // (4, 512, 64) scratch, fully overwritten

    conv_mean_kernel<<<dim3(2048), 512, 0, stream>>>(msa, Wc, bc, avg);
    pairs_kernel<<<dim3(W_, B_), 256, 0, stream>>>(avg, out);
}

// Round 8
// 75.612 us; speedup vs baseline: 1.4480x; 1.4480x over previous
//
#include <hip/hip_runtime.h>

#define B_   4
#define CIN  23
#define H_   256
#define W_   512
#define CO   64
#define HC   8                   // h-chunks of 32
#define NPART (B_ * W_ * CO)     // 131072 floats per h-chunk partial

typedef float f32x4 __attribute__((ext_vector_type(4)));
typedef _Float16 half8 __attribute__((ext_vector_type(8)));

// ---------------------------------------------------------------------------
// Kernel A: conv(23->64)+bias+relu, partial h-sum via MFMA.
// Grid (wq=32, hc=8, b=4) = 1024 blocks x 256 thr (4 waves).
// Block tile: 16 w x 32 h x ALL 64 channels -> msa read ONCE chip-wide.
// Wave mg owns co-group [16mg,16mg+16). A-frag = W (f16, zero-padded k>=23)
// lives in 4 VGPRs/lane. Per h: stage X[16w][23k] as f16 in LDS (80B rows,
// 2-way-free bank pattern), ds_read_b128 B-frag, 1 MFMA, bias+relu+acc on C.
// C layout (m89): col=lane&15 (=w), row=4*(lane>>4)+reg (=co_local).
// ---------------------------------------------------------------------------
__global__ __launch_bounds__(256) void conv_mfma_kernel(
    const float* __restrict__ msa,   // [B][CIN][H][W]
    const float* __restrict__ Wc,    // [CO][CIN]
    const float* __restrict__ bias,  // [CO]
    float* __restrict__ partial)     // [HC][B][W][CO]
{
    const int tid  = threadIdx.x;
    const int lane = tid & 63;
    const int mg   = tid >> 6;        // wave id = co-group 0..3
    const int wrow = lane & 15;       // A row (co_local base col) / B n-col (w) / C col
    const int kg   = lane >> 4;       // 0..3 : k-group (8 k each)

    const int wq = blockIdx.x;        // 0..31
    const int hc = blockIdx.y;        // 0..7
    const int b  = blockIdx.z;
    const int w0 = wq * 16;

    // A fragment: W[16*mg + wrow][8*kg + j], zero for k >= 23
    half8 afrag;
#pragma unroll
    for (int j = 0; j < 8; ++j) {
        const int k = 8 * kg + j;
        afrag[j] = (_Float16)((k < CIN) ? Wc[(16 * mg + wrow) * CIN + k] : 0.f);
    }
    // bias for this lane's 4 C rows: co = 16*mg + 4*kg + r
    float bias_r[4];
#pragma unroll
    for (int r = 0; r < 4; ++r) bias_r[r] = bias[16 * mg + 4 * kg + r];

    float acc0 = 0.f, acc1 = 0.f, acc2 = 0.f, acc3 = 0.f;

    // [h-slot][w][k] ; row stride 40 halfs = 80B (16B-aligned, 2-way-free banks)
    __shared__ __align__(16) _Float16 xs[4][16][40];

    for (int step = 0; step < 8; ++step) {
        // wave mg stages h = hc*32 + step*4 + mg
        const int hg = hc * 32 + step * 4 + mg;
        {
            const float* src = msa + ((size_t)b * CIN) * (H_ * W_) + (size_t)hg * W_ + w0 + wrow;
#pragma unroll
            for (int m = 0; m < 6; ++m) {
                const int i = kg + 4 * m;        // covers 0..23 once across kg,m
                if (i < CIN)
                    xs[mg][wrow][i] = (_Float16)src[(size_t)i * (H_ * W_)];
            }
        }
        __syncthreads();
#pragma unroll
        for (int hh = 0; hh < 4; ++hh) {
            const half8 bfrag = *(const half8*)&xs[hh][wrow][8 * kg];
            f32x4 c = {0.f, 0.f, 0.f, 0.f};
            c = __builtin_amdgcn_mfma_f32_16x16x32_f16(afrag, bfrag, c, 0, 0, 0);
            acc0 += fmaxf(c[0] + bias_r[0], 0.f);
            acc1 += fmaxf(c[1] + bias_r[1], 0.f);
            acc2 += fmaxf(c[2] + bias_r[2], 0.f);
            acc3 += fmaxf(c[3] + bias_r[3], 0.f);
        }
        __syncthreads();
    }

    // partial[hc][b][w0+wrow][16*mg + 4*kg .. +3]
    f32x4 v; v[0] = acc0; v[1] = acc1; v[2] = acc2; v[3] = acc3;
    float* dst = partial + (((size_t)hc * B_ + b) * W_ + w0 + wrow) * CO + 16 * mg + 4 * kg;
    *(f32x4*)dst = v;
}

// ---------------------------------------------------------------------------
// Kernel B: avg[b][w][c] = (1/H) * sum_hc partial[hc][b][w][c]   (float4-wide)
// ---------------------------------------------------------------------------
__global__ __launch_bounds__(256) void reduce_avg_kernel(
    const float* __restrict__ partial,  // [HC][B][W][CO]
    float* __restrict__ avg)            // [B][W][CO]
{
    const int idx = blockIdx.x * 256 + threadIdx.x;   // f32x4 index, 0..32767
    const f32x4* p4 = (const f32x4*)partial;
    f32x4 s = p4[idx];
#pragma unroll
    for (int k = 1; k < HC; ++k) s += p4[(size_t)k * (NPART / 4) + idx];
    ((f32x4*)avg)[idx] = s * (1.0f / H_);
}

// ---------------------------------------------------------------------------
// Kernel C: out[b][wi][wj][c] = avg[b][wi][c] + avg[b][wj][c]
// Grid (wi=512, b=4) x 256 thr; each wave stores 1 KiB contiguous per iter.
// ---------------------------------------------------------------------------
__global__ __launch_bounds__(256) void pairs_kernel(
    const float* __restrict__ avg,  // [B][W][CO]
    float* __restrict__ out)        // [B][W][W][CO]
{
    const int b   = blockIdx.y;
    const int wi  = blockIdx.x;
    const int tid = threadIdx.x;
    const int cq  = tid & 15;   // c-quad (64 c = 16 float4)
    const int wj0 = tid >> 4;   // 0..15

    const f32x4* a4 = (const f32x4*)avg;
    const f32x4 aI = a4[(b * W_ + wi) * 16 + cq];
    f32x4* o4 = (f32x4*)out + ((size_t)(b * W_ + wi)) * W_ * 16;

#pragma unroll 4
    for (int wj = wj0; wj < W_; wj += 16) {
        const f32x4 aJ = a4[(b * W_ + wj) * 16 + cq];
        const f32x4 r = aI + aJ;
        __builtin_nontemporal_store(r, o4 + (size_t)wj * 16 + cq);
    }
}

extern "C" void kernel_launch(void* const* d_in, const int* in_sizes, int n_in,
                              void* d_out, int out_size, void* d_ws, size_t ws_size,
                              hipStream_t stream) {
    const float* msa = (const float*)d_in[0];   // (4, 23, 256, 512)
    const float* Wc  = (const float*)d_in[1];   // (64, 23)
    const float* bc  = (const float*)d_in[2];   // (64,)
    float* out = (float*)d_out;                 // (4, 512, 512, 64)
    float* avg = (float*)d_ws;                  // (4, 512, 64) = 512 KB scratch

    // partial[8][4][512][64] = 4 MiB staged in d_out; fully overwritten by
    // pairs_kernel afterwards (stream-ordered A -> B -> C).
    float* partial = (float*)d_out;

    conv_mfma_kernel<<<dim3(32, HC, B_), 256, 0, stream>>>(msa, Wc, bc, partial);
    reduce_avg_kernel<<<dim3(NPART / 4 / 256), 256, 0, stream>>>(partial, avg);
    pairs_kernel<<<dim3(W_, B_), 256, 0, stream>>>(avg, out);
}